// Round 1
// baseline (5011.408 us; speedup 1.0000x reference)
//
#include <hip/hip_runtime.h>

#define D     128
#define NT    200000
#define NL    50000
#define ETA   1000000
#define EREV  1000000
#define ELL   500000
#define ELBL  500000

// ---------------------------------------------------------------------------
// Transpose the four 128x128 weight matrices into ws so the GEMM's per-k
// weight reads are coalesced across lanes: WT[k*128 + f] = W[f*128 + k].
// Slot order: 0 = W_l_tl, 1 = W_r_tl, 2 = W_l_ll, 3 = W_r_ll.
// ---------------------------------------------------------------------------
__global__ __launch_bounds__(256) void transpose4(
    const float* __restrict__ w0, const float* __restrict__ w1,
    const float* __restrict__ w2, const float* __restrict__ w3,
    float* __restrict__ out)
{
    const float* w = (blockIdx.x == 0) ? w0 : (blockIdx.x == 1) ? w1
                   : (blockIdx.x == 2) ? w2 : w3;
    float* o = out + (size_t)blockIdx.x * (D * D);
    for (int i = threadIdx.x; i < D * D; i += 256) {
        int k = i >> 7, f = i & 127;
        o[i] = w[f * D + k];
    }
}

// ---------------------------------------------------------------------------
// Edge-parallel scatter-add: 32 lanes per edge, float4 per lane.
// remap != nullptr applies label_node_id indirection to src indices.
// ---------------------------------------------------------------------------
__global__ __launch_bounds__(256) void scatter_kernel(
    const float* __restrict__ xsrc, const int* __restrict__ remap,
    const int* __restrict__ src, const int* __restrict__ dst,
    float* __restrict__ agg, float* __restrict__ cnt, int E)
{
    int idx = blockIdx.x * 256 + threadIdx.x;
    int e = idx >> 5;
    if (e >= E) return;
    int l = idx & 31;
    int s = src[e];
    if (remap) s = remap[s];
    int d = dst[e];
    const float4 v = *reinterpret_cast<const float4*>(xsrc + (size_t)s * D + l * 4);
    float* p = agg + (size_t)d * D + l * 4;
    unsafeAtomicAdd(p + 0, v.x);
    unsafeAtomicAdd(p + 1, v.y);
    unsafeAtomicAdd(p + 2, v.z);
    unsafeAtomicAdd(p + 3, v.w);
    if (l == 0) unsafeAtomicAdd(cnt + d, 1.0f);
}

// ---------------------------------------------------------------------------
// Label-side GEMM: out_label = relu( W_l_tl@(aggTa/cTa) + b_tl
//                                  + W_l_ll@(aggLl/cLl) + b_ll
//                                  + (W_r_tl + W_r_ll)@x_label )
// 16 rows per 128-thread block; thread t owns output feature t.
// aggTa lives in the out_label region (in-place safe: staged to LDS first).
// ---------------------------------------------------------------------------
__global__ __launch_bounds__(128) void gemm_label(
    const float* __restrict__ aggTa, const float* __restrict__ aggLl,
    const float* __restrict__ labelEmbed, const int* __restrict__ labelNodeId,
    const float* __restrict__ cntTa, const float* __restrict__ cntLl,
    const float* __restrict__ WT,
    const float* __restrict__ b_tl, const float* __restrict__ b_ll,
    float* __restrict__ outLabel)
{
    __shared__ float xs[16 * D];
    __shared__ float ata[16 * D];
    __shared__ float all_[16 * D];
    const int t = threadIdx.x;
    const int r0 = blockIdx.x * 16;

    for (int i = t; i < 16 * 32; i += 128) {          // 512 float4 slots
        int r = i >> 5, k4 = (i & 31) * 4;
        int row = r0 + r;
        float rTa = 1.0f / fmaxf(cntTa[row], 1.0f);
        float rLl = 1.0f / fmaxf(cntLl[row], 1.0f);
        int xr = labelNodeId[row];
        float4 a = *reinterpret_cast<const float4*>(aggTa + (size_t)row * D + k4);
        float4 b = *reinterpret_cast<const float4*>(aggLl + (size_t)row * D + k4);
        float4 x = *reinterpret_cast<const float4*>(labelEmbed + (size_t)xr * D + k4);
        *reinterpret_cast<float4*>(&ata[r * D + k4]) =
            make_float4(a.x * rTa, a.y * rTa, a.z * rTa, a.w * rTa);
        *reinterpret_cast<float4*>(&all_[r * D + k4]) =
            make_float4(b.x * rLl, b.y * rLl, b.z * rLl, b.w * rLl);
        *reinterpret_cast<float4*>(&xs[r * D + k4]) = x;
    }
    __syncthreads();

    const float* WTlt  = WT;
    const float* WTrt  = WT + D * D;
    const float* WTlll = WT + 2 * D * D;
    const float* WTllr = WT + 3 * D * D;

    float acc[16];
    float bias = b_tl[t] + b_ll[t];
#pragma unroll
    for (int r = 0; r < 16; ++r) acc[r] = bias;

    for (int k4 = 0; k4 < D; k4 += 4) {
        float w0[4], w2[4], w13[4];
#pragma unroll
        for (int j = 0; j < 4; ++j) {
            w0[j]  = WTlt[(k4 + j) * D + t];
            w13[j] = WTrt[(k4 + j) * D + t] + WTllr[(k4 + j) * D + t];
            w2[j]  = WTlll[(k4 + j) * D + t];
        }
#pragma unroll
        for (int r = 0; r < 16; ++r) {
            float4 xv = *reinterpret_cast<const float4*>(&xs[r * D + k4]);
            float4 av = *reinterpret_cast<const float4*>(&ata[r * D + k4]);
            float4 lv = *reinterpret_cast<const float4*>(&all_[r * D + k4]);
            acc[r] += w0[0] * av.x + w0[1] * av.y + w0[2] * av.z + w0[3] * av.w
                    + w2[0] * lv.x + w2[1] * lv.y + w2[2] * lv.z + w2[3] * lv.w
                    + w13[0] * xv.x + w13[1] * xv.y + w13[2] * xv.z + w13[3] * xv.w;
        }
    }
#pragma unroll
    for (int r = 0; r < 16; ++r)
        outLabel[(size_t)(r0 + r) * D + t] = fmaxf(acc[r], 0.0f);
}

// ---------------------------------------------------------------------------
// Title-side GEMM: out_title = relu( W_l_tl@(aggRev/cRev) + b_tl + W_r_tl@x_title )
// aggRev lives in the out_title region (in-place safe).
// ---------------------------------------------------------------------------
__global__ __launch_bounds__(128) void gemm_title(
    const float* __restrict__ aggRev, const float* __restrict__ xTitle,
    const float* __restrict__ cntRev, const float* __restrict__ WT,
    const float* __restrict__ b_tl, float* __restrict__ outTitle)
{
    __shared__ float xs[16 * D];
    __shared__ float arv[16 * D];
    const int t = threadIdx.x;
    const int r0 = blockIdx.x * 16;

    for (int i = t; i < 16 * 32; i += 128) {
        int r = i >> 5, k4 = (i & 31) * 4;
        int row = r0 + r;
        float rC = 1.0f / fmaxf(cntRev[row], 1.0f);
        float4 a = *reinterpret_cast<const float4*>(aggRev + (size_t)row * D + k4);
        float4 x = *reinterpret_cast<const float4*>(xTitle + (size_t)row * D + k4);
        *reinterpret_cast<float4*>(&arv[r * D + k4]) =
            make_float4(a.x * rC, a.y * rC, a.z * rC, a.w * rC);
        *reinterpret_cast<float4*>(&xs[r * D + k4]) = x;
    }
    __syncthreads();

    const float* WTlt = WT;
    const float* WTrt = WT + D * D;

    float acc[16];
    float bias = b_tl[t];
#pragma unroll
    for (int r = 0; r < 16; ++r) acc[r] = bias;

    for (int k4 = 0; k4 < D; k4 += 4) {
        float w0[4], w1[4];
#pragma unroll
        for (int j = 0; j < 4; ++j) {
            w0[j] = WTlt[(k4 + j) * D + t];
            w1[j] = WTrt[(k4 + j) * D + t];
        }
#pragma unroll
        for (int r = 0; r < 16; ++r) {
            float4 xv = *reinterpret_cast<const float4*>(&xs[r * D + k4]);
            float4 av = *reinterpret_cast<const float4*>(&arv[r * D + k4]);
            acc[r] += w0[0] * av.x + w0[1] * av.y + w0[2] * av.z + w0[3] * av.w
                    + w1[0] * xv.x + w1[1] * xv.y + w1[2] * xv.z + w1[3] * xv.w;
        }
    }
#pragma unroll
    for (int r = 0; r < 16; ++r)
        outTitle[(size_t)(r0 + r) * D + t] = fmaxf(acc[r], 0.0f);
}

// ---------------------------------------------------------------------------
// Supervision-edge dot products: 32 lanes per edge, float4 per lane,
// shuffle-reduce within the 32-lane group.
// ---------------------------------------------------------------------------
__global__ __launch_bounds__(256) void pred_kernel(
    const float* __restrict__ outTitle, const float* __restrict__ outLabel,
    const int* __restrict__ elSrc, const int* __restrict__ elDst,
    float* __restrict__ pred, int E)
{
    int idx = blockIdx.x * 256 + threadIdx.x;
    int e = idx >> 5;
    if (e >= E) return;
    int l = idx & 31;
    int s = elSrc[e];
    int d = elDst[e];
    float4 a = *reinterpret_cast<const float4*>(outTitle + (size_t)s * D + l * 4);
    float4 b = *reinterpret_cast<const float4*>(outLabel + (size_t)d * D + l * 4);
    float v = a.x * b.x + a.y * b.y + a.z * b.z + a.w * b.w;
#pragma unroll
    for (int off = 16; off > 0; off >>= 1) v += __shfl_down(v, off, 32);
    if (l == 0) pred[e] = v;
}

// ---------------------------------------------------------------------------
extern "C" void kernel_launch(void* const* d_in, const int* in_sizes, int n_in,
                              void* d_out, int out_size, void* d_ws, size_t ws_size,
                              hipStream_t stream)
{
    const float* x_title       = (const float*)d_in[0];
    const float* label_embed   = (const float*)d_in[1];
    const float* W_l_tl        = (const float*)d_in[2];
    const float* b_l_tl        = (const float*)d_in[3];
    const float* W_r_tl        = (const float*)d_in[4];
    const float* W_l_ll        = (const float*)d_in[5];
    const float* b_l_ll        = (const float*)d_in[6];
    const float* W_r_ll        = (const float*)d_in[7];
    const int*   label_node_id = (const int*)d_in[8];
    const int*   ta_src        = (const int*)d_in[9];
    const int*   ta_dst        = (const int*)d_in[10];
    const int*   rev_src       = (const int*)d_in[11];
    const int*   rev_dst       = (const int*)d_in[12];
    const int*   ll_src        = (const int*)d_in[13];
    const int*   ll_dst        = (const int*)d_in[14];
    const int*   el_src        = (const int*)d_in[15];
    const int*   el_dst        = (const int*)d_in[16];

    float* out       = (float*)d_out;
    float* pred      = out;                       // [ELBL]
    float* out_title = out + ELBL;                // [NT*D] — doubles as aggRev
    float* out_label = out_title + (size_t)NT * D;// [NL*D] — doubles as aggTa

    float* ws     = (float*)d_ws;
    float* aggLl  = ws;                           // NL*D floats
    float* cntTa  = aggLl + (size_t)NL * D;       // NL
    float* cntLl  = cntTa + NL;                   // NL
    float* cntRev = cntLl + NL;                   // NT
    float* WT     = cntRev + NT;                  // 4 * D*D floats

    // Zero the accumulators (ws and d_out are poisoned 0xAA before each call).
    hipMemsetAsync(ws, 0, ((size_t)NL * D + NL + NL + NT) * sizeof(float), stream);
    hipMemsetAsync(out_title, 0, ((size_t)NT * D + (size_t)NL * D) * sizeof(float), stream);

    transpose4<<<4, 256, 0, stream>>>(W_l_tl, W_r_tl, W_l_ll, W_r_ll, WT);

    // Aggregations (edge-parallel atomics).
    scatter_kernel<<<(ETA * 32) / 256, 256, 0, stream>>>(
        x_title, nullptr, ta_src, ta_dst, out_label /*aggTa*/, cntTa, ETA);
    scatter_kernel<<<(ELL * 32) / 256, 256, 0, stream>>>(
        label_embed, label_node_id, ll_src, ll_dst, aggLl, cntLl, ELL);
    scatter_kernel<<<(EREV * 32) / 256, 256, 0, stream>>>(
        label_embed, label_node_id, rev_src, rev_dst, out_title /*aggRev*/, cntRev, EREV);

    // Linear layers + bias + ReLU (in-place over agg regions).
    gemm_label<<<NL / 16, 128, 0, stream>>>(
        out_label, aggLl, label_embed, label_node_id, cntTa, cntLl,
        WT, b_l_tl, b_l_ll, out_label);
    gemm_title<<<NT / 16, 128, 0, stream>>>(
        out_title, x_title, cntRev, WT, b_l_tl, out_title);

    // Supervision-edge dot products.
    pred_kernel<<<(ELBL * 32) / 256, 256, 0, stream>>>(
        out_title, out_label, el_src, el_dst, pred, ELBL);
}

// Round 2
// 1502.424 us; speedup vs baseline: 3.3355x; 3.3355x over previous
//
#include <hip/hip_runtime.h>

#define D     128
#define NT    200000
#define NL    50000
#define ETA   1000000
#define EREV  1000000
#define ELL   500000
#define ELBL  500000

// ---------------------------------------------------------------------------
// Transpose the four 128x128 weight matrices into ws so the GEMM's per-k
// weight reads are coalesced across lanes: WT[k*128 + f] = W[f*128 + k].
// Slot order: 0 = W_l_tl, 1 = W_r_tl, 2 = W_l_ll, 3 = W_r_ll.
// ---------------------------------------------------------------------------
__global__ __launch_bounds__(256) void transpose4(
    const float* __restrict__ w0, const float* __restrict__ w1,
    const float* __restrict__ w2, const float* __restrict__ w3,
    float* __restrict__ out)
{
    const float* w = (blockIdx.x == 0) ? w0 : (blockIdx.x == 1) ? w1
                   : (blockIdx.x == 2) ? w2 : w3;
    float* o = out + (size_t)blockIdx.x * (D * D);
    for (int i = threadIdx.x; i < D * D; i += 256) {
        int k = i >> 7, f = i & 127;
        o[i] = w[f * D + k];
    }
}

// ---------------------------------------------------------------------------
// Degree count: 1 thread per edge, int atomic.
// ---------------------------------------------------------------------------
__global__ __launch_bounds__(256) void count_kernel(
    const int* __restrict__ dst, int* __restrict__ cnt, int E)
{
    int e = blockIdx.x * 256 + threadIdx.x;
    if (e >= E) return;
    atomicAdd(&cnt[dst[e]], 1);
}

// ---------------------------------------------------------------------------
// Exclusive scan of the three degree arrays into cursor arrays.
// One 1024-thread block per array: chunked serial sums + LDS Hillis-Steele.
// ---------------------------------------------------------------------------
__global__ __launch_bounds__(1024) void scan3(
    const int* __restrict__ cntTa, const int* __restrict__ cntLl,
    const int* __restrict__ cntRev,
    int* __restrict__ curTa, int* __restrict__ curLl, int* __restrict__ curRev)
{
    const int* cnt; int* cur; int n;
    if (blockIdx.x == 0)      { cnt = cntTa;  cur = curTa;  n = NL; }
    else if (blockIdx.x == 1) { cnt = cntLl;  cur = curLl;  n = NL; }
    else                      { cnt = cntRev; cur = curRev; n = NT; }
    const int t = threadIdx.x;
    const int chunk = (n + 1023) >> 10;
    const int lo = t * chunk;
    const int hi = min(lo + chunk, n);
    int s = 0;
    for (int i = lo; i < hi; ++i) s += cnt[i];
    __shared__ int sums[1024];
    sums[t] = s;
    __syncthreads();
    for (int off = 1; off < 1024; off <<= 1) {
        int add = (t >= off) ? sums[t - off] : 0;
        __syncthreads();
        sums[t] += add;
        __syncthreads();
    }
    int run = (t == 0) ? 0 : sums[t - 1];   // exclusive prefix for this chunk
    for (int i = lo; i < hi; ++i) { cur[i] = run; run += cnt[i]; }
}

// ---------------------------------------------------------------------------
// CSR fill: ticket into cursor, write (remapped) src id.
// After this kernel, cur[row] == segment end; start = end - cnt[row].
// ---------------------------------------------------------------------------
__global__ __launch_bounds__(256) void fill_kernel(
    const int* __restrict__ src, const int* __restrict__ dst,
    const int* __restrict__ remap, int* __restrict__ cur,
    int* __restrict__ csr, int E)
{
    int e = blockIdx.x * 256 + threadIdx.x;
    if (e >= E) return;
    int s = src[e];
    if (remap) s = remap[s];
    int pos = atomicAdd(&cur[dst[e]], 1);
    csr[pos] = s;
}

// ---------------------------------------------------------------------------
// Segmented mean: one wave per dst row, float2 per lane, no atomics.
// Writes the MEAN (already divided) — downstream GEMM needs no counts.
// Rows with degree 0 get zeros (also removes the need for a big memset).
// ---------------------------------------------------------------------------
__global__ __launch_bounds__(256) void agg_kernel(
    const float* __restrict__ xsrc, const int* __restrict__ csr,
    const int* __restrict__ cnt, const int* __restrict__ cur,
    float* __restrict__ agg, int n)
{
    int row = blockIdx.x * 4 + (threadIdx.x >> 6);
    if (row >= n) return;
    int lane = threadIdx.x & 63;
    int deg = cnt[row];
    int end = cur[row];
    int e = end - deg;
    float accx = 0.f, accy = 0.f;
    for (; e + 1 < end; e += 2) {
        int s0 = csr[e], s1 = csr[e + 1];
        float2 v0 = *reinterpret_cast<const float2*>(xsrc + (size_t)s0 * D + lane * 2);
        float2 v1 = *reinterpret_cast<const float2*>(xsrc + (size_t)s1 * D + lane * 2);
        accx += v0.x + v1.x;
        accy += v0.y + v1.y;
    }
    if (e < end) {
        int s0 = csr[e];
        float2 v0 = *reinterpret_cast<const float2*>(xsrc + (size_t)s0 * D + lane * 2);
        accx += v0.x;
        accy += v0.y;
    }
    float r = 1.0f / fmaxf((float)deg, 1.0f);
    *reinterpret_cast<float2*>(agg + (size_t)row * D + lane * 2) =
        make_float2(accx * r, accy * r);
}

// ---------------------------------------------------------------------------
// Label-side GEMM: out_label = relu( W_l_tl@meanTa + b_tl
//                                  + W_l_ll@meanLl + b_ll
//                                  + (W_r_tl + W_r_ll)@x_label )
// 16 rows per 128-thread block; thread t owns output feature t.
// meanTa lives in the out_label region (in-place safe: staged to LDS first).
// ---------------------------------------------------------------------------
__global__ __launch_bounds__(128) void gemm_label(
    const float* __restrict__ meanTa, const float* __restrict__ meanLl,
    const float* __restrict__ labelEmbed, const int* __restrict__ labelNodeId,
    const float* __restrict__ WT,
    const float* __restrict__ b_tl, const float* __restrict__ b_ll,
    float* __restrict__ outLabel)
{
    __shared__ float xs[16 * D];
    __shared__ float ata[16 * D];
    __shared__ float all_[16 * D];
    const int t = threadIdx.x;
    const int r0 = blockIdx.x * 16;

    for (int i = t; i < 16 * 32; i += 128) {          // 512 float4 slots
        int r = i >> 5, k4 = (i & 31) * 4;
        int row = r0 + r;
        int xr = labelNodeId[row];
        *reinterpret_cast<float4*>(&ata[r * D + k4]) =
            *reinterpret_cast<const float4*>(meanTa + (size_t)row * D + k4);
        *reinterpret_cast<float4*>(&all_[r * D + k4]) =
            *reinterpret_cast<const float4*>(meanLl + (size_t)row * D + k4);
        *reinterpret_cast<float4*>(&xs[r * D + k4]) =
            *reinterpret_cast<const float4*>(labelEmbed + (size_t)xr * D + k4);
    }
    __syncthreads();

    const float* WTlt  = WT;
    const float* WTrt  = WT + D * D;
    const float* WTlll = WT + 2 * D * D;
    const float* WTllr = WT + 3 * D * D;

    float acc[16];
    float bias = b_tl[t] + b_ll[t];
#pragma unroll
    for (int r = 0; r < 16; ++r) acc[r] = bias;

    for (int k4 = 0; k4 < D; k4 += 4) {
        float w0[4], w2[4], w13[4];
#pragma unroll
        for (int j = 0; j < 4; ++j) {
            w0[j]  = WTlt[(k4 + j) * D + t];
            w13[j] = WTrt[(k4 + j) * D + t] + WTllr[(k4 + j) * D + t];
            w2[j]  = WTlll[(k4 + j) * D + t];
        }
#pragma unroll
        for (int r = 0; r < 16; ++r) {
            float4 xv = *reinterpret_cast<const float4*>(&xs[r * D + k4]);
            float4 av = *reinterpret_cast<const float4*>(&ata[r * D + k4]);
            float4 lv = *reinterpret_cast<const float4*>(&all_[r * D + k4]);
            acc[r] += w0[0] * av.x + w0[1] * av.y + w0[2] * av.z + w0[3] * av.w
                    + w2[0] * lv.x + w2[1] * lv.y + w2[2] * lv.z + w2[3] * lv.w
                    + w13[0] * xv.x + w13[1] * xv.y + w13[2] * xv.z + w13[3] * xv.w;
        }
    }
#pragma unroll
    for (int r = 0; r < 16; ++r)
        outLabel[(size_t)(r0 + r) * D + t] = fmaxf(acc[r], 0.0f);
}

// ---------------------------------------------------------------------------
// Title-side GEMM: out_title = relu( W_l_tl@meanRev + b_tl + W_r_tl@x_title )
// meanRev lives in the out_title region (in-place safe).
// ---------------------------------------------------------------------------
__global__ __launch_bounds__(128) void gemm_title(
    const float* __restrict__ meanRev, const float* __restrict__ xTitle,
    const float* __restrict__ WT,
    const float* __restrict__ b_tl, float* __restrict__ outTitle)
{
    __shared__ float xs[16 * D];
    __shared__ float arv[16 * D];
    const int t = threadIdx.x;
    const int r0 = blockIdx.x * 16;

    for (int i = t; i < 16 * 32; i += 128) {
        int r = i >> 5, k4 = (i & 31) * 4;
        int row = r0 + r;
        *reinterpret_cast<float4*>(&arv[r * D + k4]) =
            *reinterpret_cast<const float4*>(meanRev + (size_t)row * D + k4);
        *reinterpret_cast<float4*>(&xs[r * D + k4]) =
            *reinterpret_cast<const float4*>(xTitle + (size_t)row * D + k4);
    }
    __syncthreads();

    const float* WTlt = WT;
    const float* WTrt = WT + D * D;

    float acc[16];
    float bias = b_tl[t];
#pragma unroll
    for (int r = 0; r < 16; ++r) acc[r] = bias;

    for (int k4 = 0; k4 < D; k4 += 4) {
        float w0[4], w1[4];
#pragma unroll
        for (int j = 0; j < 4; ++j) {
            w0[j] = WTlt[(k4 + j) * D + t];
            w1[j] = WTrt[(k4 + j) * D + t];
        }
#pragma unroll
        for (int r = 0; r < 16; ++r) {
            float4 xv = *reinterpret_cast<const float4*>(&xs[r * D + k4]);
            float4 av = *reinterpret_cast<const float4*>(&arv[r * D + k4]);
            acc[r] += w0[0] * av.x + w0[1] * av.y + w0[2] * av.z + w0[3] * av.w
                    + w1[0] * xv.x + w1[1] * xv.y + w1[2] * xv.z + w1[3] * xv.w;
        }
    }
#pragma unroll
    for (int r = 0; r < 16; ++r)
        outTitle[(size_t)(r0 + r) * D + t] = fmaxf(acc[r], 0.0f);
}

// ---------------------------------------------------------------------------
// Supervision-edge dot products: 32 lanes per edge, float4 per lane,
// shuffle-reduce within the 32-lane group.
// ---------------------------------------------------------------------------
__global__ __launch_bounds__(256) void pred_kernel(
    const float* __restrict__ outTitle, const float* __restrict__ outLabel,
    const int* __restrict__ elSrc, const int* __restrict__ elDst,
    float* __restrict__ pred, int E)
{
    int idx = blockIdx.x * 256 + threadIdx.x;
    int e = idx >> 5;
    if (e >= E) return;
    int l = idx & 31;
    int s = elSrc[e];
    int d = elDst[e];
    float4 a = *reinterpret_cast<const float4*>(outTitle + (size_t)s * D + l * 4);
    float4 b = *reinterpret_cast<const float4*>(outLabel + (size_t)d * D + l * 4);
    float v = a.x * b.x + a.y * b.y + a.z * b.z + a.w * b.w;
#pragma unroll
    for (int off = 16; off > 0; off >>= 1) v += __shfl_down(v, off, 32);
    if (l == 0) pred[e] = v;
}

// ---------------------------------------------------------------------------
extern "C" void kernel_launch(void* const* d_in, const int* in_sizes, int n_in,
                              void* d_out, int out_size, void* d_ws, size_t ws_size,
                              hipStream_t stream)
{
    const float* x_title       = (const float*)d_in[0];
    const float* label_embed   = (const float*)d_in[1];
    const float* W_l_tl        = (const float*)d_in[2];
    const float* b_l_tl        = (const float*)d_in[3];
    const float* W_r_tl        = (const float*)d_in[4];
    const float* W_l_ll        = (const float*)d_in[5];
    const float* b_l_ll        = (const float*)d_in[6];
    const float* W_r_ll        = (const float*)d_in[7];
    const int*   label_node_id = (const int*)d_in[8];
    const int*   ta_src        = (const int*)d_in[9];
    const int*   ta_dst        = (const int*)d_in[10];
    const int*   rev_src       = (const int*)d_in[11];
    const int*   rev_dst       = (const int*)d_in[12];
    const int*   ll_src        = (const int*)d_in[13];
    const int*   ll_dst        = (const int*)d_in[14];
    const int*   el_src        = (const int*)d_in[15];
    const int*   el_dst        = (const int*)d_in[16];

    float* out       = (float*)d_out;
    float* pred      = out;                        // [ELBL]
    float* out_title = out + ELBL;                 // [NT*D] — doubles as meanRev
    float* out_label = out_title + (size_t)NT * D; // [NL*D] — doubles as meanTa

    // Workspace layout.
    float* ws     = (float*)d_ws;
    float* WT     = ws;                            // 4*D*D floats
    float* meanLl = WT + 4 * D * D;                // NL*D floats
    int*   cntTa  = (int*)(meanLl + (size_t)NL * D); // NL
    int*   cntLl  = cntTa + NL;                    // NL
    int*   cntRev = cntLl + NL;                    // NT
    int*   curTa  = cntRev + NT;                   // NL
    int*   curLl  = curTa + NL;                    // NL
    int*   curRev = curLl + NL;                    // NT
    int*   csrTa  = curRev + NT;                   // ETA
    int*   csrLl  = csrTa + ETA;                   // ELL
    int*   csrRev = csrLl + ELL;                   // EREV

    // Zero only the degree counters (everything else is fully overwritten).
    hipMemsetAsync(cntTa, 0, (size_t)(NL + NL + NT) * sizeof(int), stream);

    transpose4<<<4, 256, 0, stream>>>(W_l_tl, W_r_tl, W_l_ll, W_r_ll, WT);

    // Degree histograms.
    count_kernel<<<(ETA  + 255) / 256, 256, 0, stream>>>(ta_dst,  cntTa,  ETA);
    count_kernel<<<(ELL  + 255) / 256, 256, 0, stream>>>(ll_dst,  cntLl,  ELL);
    count_kernel<<<(EREV + 255) / 256, 256, 0, stream>>>(rev_dst, cntRev, EREV);

    // Exclusive scans -> cursors.
    scan3<<<3, 1024, 0, stream>>>(cntTa, cntLl, cntRev, curTa, curLl, curRev);

    // CSR fills (cursor becomes segment end).
    fill_kernel<<<(ETA  + 255) / 256, 256, 0, stream>>>(ta_src,  ta_dst,  nullptr,       curTa,  csrTa,  ETA);
    fill_kernel<<<(ELL  + 255) / 256, 256, 0, stream>>>(ll_src,  ll_dst,  label_node_id, curLl,  csrLl,  ELL);
    fill_kernel<<<(EREV + 255) / 256, 256, 0, stream>>>(rev_src, rev_dst, label_node_id, curRev, csrRev, EREV);

    // Gather-based segmented means (no atomics).
    agg_kernel<<<(NL + 3) / 4, 256, 0, stream>>>(x_title,     csrTa,  cntTa,  curTa,  out_label /*meanTa*/, NL);
    agg_kernel<<<(NL + 3) / 4, 256, 0, stream>>>(label_embed, csrLl,  cntLl,  curLl,  meanLl,               NL);
    agg_kernel<<<(NT + 3) / 4, 256, 0, stream>>>(label_embed, csrRev, cntRev, curRev, out_title /*meanRev*/, NT);

    // Linear layers + bias + ReLU (in-place over mean regions).
    gemm_label<<<NL / 16, 128, 0, stream>>>(
        out_label, meanLl, label_embed, label_node_id, WT, b_l_tl, b_l_ll, out_label);
    gemm_title<<<NT / 16, 128, 0, stream>>>(
        out_title, x_title, WT, b_l_tl, out_title);

    // Supervision-edge dot products.
    pred_kernel<<<(ELBL * 32) / 256, 256, 0, stream>>>(
        out_title, out_label, el_src, el_dst, pred, ELBL);
}

// Round 3
// 1038.639 us; speedup vs baseline: 4.8250x; 1.4465x over previous
//
#include <hip/hip_runtime.h>

#define D     128
#define NT    200000
#define NL    50000
#define ETA   1000000
#define EREV  1000000
#define ELL   500000
#define ELBL  500000

typedef __attribute__((ext_vector_type(8))) __bf16 bf16x8;
typedef __attribute__((ext_vector_type(4))) float f32x4;

__device__ inline bf16x8 cvt8(float4 a, float4 b)
{
    bf16x8 r;
    r[0] = (__bf16)a.x; r[1] = (__bf16)a.y; r[2] = (__bf16)a.z; r[3] = (__bf16)a.w;
    r[4] = (__bf16)b.x; r[5] = (__bf16)b.y; r[6] = (__bf16)b.z; r[7] = (__bf16)b.w;
    return r;
}

// ---------------------------------------------------------------------------
// Weight prep: convert the four 128x128 fp32 weights to bf16 in [n][k] layout
// (their native layout — MFMA B-fragment reads 8 consecutive k for n=lane&15).
// Slot 0 = W_l_tl, 1 = W_r_tl, 2 = W_l_ll, 3 = W_r_tl + W_r_ll.
// Also bias_sum = b_tl + b_ll.
// ---------------------------------------------------------------------------
__global__ __launch_bounds__(256) void prep_weights(
    const float* __restrict__ Wl_tl, const float* __restrict__ Wr_tl,
    const float* __restrict__ Wl_ll, const float* __restrict__ Wr_ll,
    const float* __restrict__ b_tl, const float* __restrict__ b_ll,
    __bf16* __restrict__ Wb, float* __restrict__ bias_sum)
{
    int i = blockIdx.x * 256 + threadIdx.x;
    if (i < D * D) {
        Wb[i]             = (__bf16)Wl_tl[i];
        Wb[D * D + i]     = (__bf16)Wr_tl[i];
        Wb[2 * D * D + i] = (__bf16)Wl_ll[i];
        Wb[3 * D * D + i] = (__bf16)(Wr_tl[i] + Wr_ll[i]);
    }
    if (i < D) bias_sum[i] = b_tl[i] + b_ll[i];
}

// ---------------------------------------------------------------------------
// Degree count: 1 thread per edge, int atomic.
// ---------------------------------------------------------------------------
__global__ __launch_bounds__(256) void count_kernel(
    const int* __restrict__ dst, int* __restrict__ cnt, int E)
{
    int e = blockIdx.x * 256 + threadIdx.x;
    if (e >= E) return;
    atomicAdd(&cnt[dst[e]], 1);
}

// ---------------------------------------------------------------------------
// Segment allocation WITHOUT a global scan: segments need not be in row
// order, so each wave prefix-sums its 64 degrees and grabs a chunk of the
// csr space with ONE atomicAdd. cur[row] = segment start.
// ---------------------------------------------------------------------------
__global__ __launch_bounds__(256) void alloc_kernel(
    const int* __restrict__ cnt, int* __restrict__ cur,
    int* __restrict__ gcnt, int n)
{
    int i = blockIdx.x * 256 + threadIdx.x;
    int lane = threadIdx.x & 63;
    int deg = (i < n) ? cnt[i] : 0;
    int incl = deg;
#pragma unroll
    for (int off = 1; off < 64; off <<= 1) {
        int v = __shfl_up(incl, off, 64);
        if (lane >= off) incl += v;
    }
    int excl = incl - deg;
    int total = __shfl(incl, 63, 64);
    int base = 0;
    if (lane == 63) base = atomicAdd(gcnt, total);
    base = __shfl(base, 63, 64);
    if (i < n) cur[i] = base + excl;
}

// ---------------------------------------------------------------------------
// CSR fill: ticket into cursor, write (remapped) src id.
// After this kernel, cur[row] == segment end; start = end - cnt[row].
// ---------------------------------------------------------------------------
__global__ __launch_bounds__(256) void fill_kernel(
    const int* __restrict__ src, const int* __restrict__ dst,
    const int* __restrict__ remap, int* __restrict__ cur,
    int* __restrict__ csr, int E)
{
    int e = blockIdx.x * 256 + threadIdx.x;
    if (e >= E) return;
    int s = src[e];
    if (remap) s = remap[s];
    int pos = atomicAdd(&cur[dst[e]], 1);
    csr[pos] = s;
}

// ---------------------------------------------------------------------------
// Segmented mean: one wave per dst row, float2 per lane, no atomics.
// Writes the MEAN (already divided). Rows with degree 0 get zeros.
// ---------------------------------------------------------------------------
__global__ __launch_bounds__(256) void agg_kernel(
    const float* __restrict__ xsrc, const int* __restrict__ csr,
    const int* __restrict__ cnt, const int* __restrict__ cur,
    float* __restrict__ agg, int n)
{
    int row = blockIdx.x * 4 + (threadIdx.x >> 6);
    if (row >= n) return;
    int lane = threadIdx.x & 63;
    int deg = cnt[row];
    int end = cur[row];
    int e = end - deg;
    float accx = 0.f, accy = 0.f;
    for (; e + 1 < end; e += 2) {
        int s0 = csr[e], s1 = csr[e + 1];
        float2 v0 = *reinterpret_cast<const float2*>(xsrc + (size_t)s0 * D + lane * 2);
        float2 v1 = *reinterpret_cast<const float2*>(xsrc + (size_t)s1 * D + lane * 2);
        accx += v0.x + v1.x;
        accy += v0.y + v1.y;
    }
    if (e < end) {
        int s0 = csr[e];
        float2 v0 = *reinterpret_cast<const float2*>(xsrc + (size_t)s0 * D + lane * 2);
        accx += v0.x;
        accy += v0.y;
    }
    float r = 1.0f / fmaxf((float)deg, 1.0f);
    *reinterpret_cast<float2*>(agg + (size_t)row * D + lane * 2) =
        make_float2(accx * r, accy * r);
}

// ---------------------------------------------------------------------------
// MFMA GEMM, title side: out = relu(meanRev @ Wl^T + b_tl + x @ Wr^T).
// 256 threads = 4 waves; block covers 32 rows x 128 cols.
// Wave w: mtile = w&1 (16 rows), ntiles (w>>1)*4 .. +3 (64 cols).
// A-frags loaded from fp32 global, converted to bf16 in-register.
// meanRev aliases outTitle: one barrier between A-reads and C-writes.
// ---------------------------------------------------------------------------
__global__ __launch_bounds__(256) void gemm_title_mfma(
    const float* __restrict__ meanRev, const float* __restrict__ xTitle,
    const __bf16* __restrict__ Wb, const float* __restrict__ b_tl,
    float* __restrict__ outTitle)
{
    const int w = threadIdx.x >> 6;
    const int lane = threadIdx.x & 63;
    const int m15 = lane & 15, q = lane >> 4;
    const int mtile = w & 1;
    const int n0 = (w >> 1) * 64;
    const int r0 = blockIdx.x * 32;
    const int rowA = r0 + mtile * 16 + m15;

    bf16x8 aM[4], aX[4];
    const float* pm = meanRev + (size_t)rowA * D + q * 8;
    const float* px = xTitle + (size_t)rowA * D + q * 8;
#pragma unroll
    for (int kc = 0; kc < 4; ++kc) {
        float4 f0 = *reinterpret_cast<const float4*>(pm + kc * 32);
        float4 f1 = *reinterpret_cast<const float4*>(pm + kc * 32 + 4);
        aM[kc] = cvt8(f0, f1);
        float4 g0 = *reinterpret_cast<const float4*>(px + kc * 32);
        float4 g1 = *reinterpret_cast<const float4*>(px + kc * 32 + 4);
        aX[kc] = cvt8(g0, g1);
    }
    __syncthreads();   // all meanRev reads complete before any outTitle write

    f32x4 acc[4] = {{0.f,0.f,0.f,0.f},{0.f,0.f,0.f,0.f},{0.f,0.f,0.f,0.f},{0.f,0.f,0.f,0.f}};
    const __bf16* W0 = Wb;            // W_l_tl [n][k]
    const __bf16* W1 = Wb + D * D;    // W_r_tl [n][k]
#pragma unroll
    for (int kc = 0; kc < 4; ++kc) {
#pragma unroll
        for (int nt = 0; nt < 4; ++nt) {
            int n = n0 + nt * 16 + m15;
            bf16x8 b0 = *reinterpret_cast<const bf16x8*>(W0 + n * D + kc * 32 + q * 8);
            bf16x8 b1 = *reinterpret_cast<const bf16x8*>(W1 + n * D + kc * 32 + q * 8);
            acc[nt] = __builtin_amdgcn_mfma_f32_16x16x32_bf16(aM[kc], b0, acc[nt], 0, 0, 0);
            acc[nt] = __builtin_amdgcn_mfma_f32_16x16x32_bf16(aX[kc], b1, acc[nt], 0, 0, 0);
        }
    }
#pragma unroll
    for (int nt = 0; nt < 4; ++nt) {
        float bias = b_tl[n0 + nt * 16 + m15];
#pragma unroll
        for (int rg = 0; rg < 4; ++rg) {
            int row = r0 + mtile * 16 + q * 4 + rg;
            outTitle[(size_t)row * D + n0 + nt * 16 + m15] = fmaxf(acc[nt][rg] + bias, 0.0f);
        }
    }
}

// ---------------------------------------------------------------------------
// MFMA GEMM, label side: out = relu(meanTa @ Wl_tl^T + b_tl
//                                 + meanLl @ Wl_ll^T + b_ll
//                                 + x_label @ (Wr_tl+Wr_ll)^T).
// meanTa aliases outLabel (barrier). Last block is partial (guarded).
// ---------------------------------------------------------------------------
__global__ __launch_bounds__(256) void gemm_label_mfma(
    const float* __restrict__ meanTa, const float* __restrict__ meanLl,
    const float* __restrict__ labelEmbed, const int* __restrict__ labelNodeId,
    const __bf16* __restrict__ Wb, const float* __restrict__ bias_sum,
    float* __restrict__ outLabel)
{
    const int w = threadIdx.x >> 6;
    const int lane = threadIdx.x & 63;
    const int m15 = lane & 15, q = lane >> 4;
    const int mtile = w & 1;
    const int n0 = (w >> 1) * 64;
    const int r0 = blockIdx.x * 32;
    int rowA = r0 + mtile * 16 + m15;
    if (rowA >= NL) rowA = NL - 1;           // clamp (partial last block)
    const int xr = labelNodeId[rowA];

    bf16x8 aT[4], aL[4], aXl[4];
    const float* pt = meanTa + (size_t)rowA * D + q * 8;
    const float* pl = meanLl + (size_t)rowA * D + q * 8;
    const float* pe = labelEmbed + (size_t)xr * D + q * 8;
#pragma unroll
    for (int kc = 0; kc < 4; ++kc) {
        float4 f0 = *reinterpret_cast<const float4*>(pt + kc * 32);
        float4 f1 = *reinterpret_cast<const float4*>(pt + kc * 32 + 4);
        aT[kc] = cvt8(f0, f1);
        float4 g0 = *reinterpret_cast<const float4*>(pl + kc * 32);
        float4 g1 = *reinterpret_cast<const float4*>(pl + kc * 32 + 4);
        aL[kc] = cvt8(g0, g1);
        float4 h0 = *reinterpret_cast<const float4*>(pe + kc * 32);
        float4 h1 = *reinterpret_cast<const float4*>(pe + kc * 32 + 4);
        aXl[kc] = cvt8(h0, h1);
    }
    __syncthreads();   // all meanTa reads complete before any outLabel write

    f32x4 acc[4] = {{0.f,0.f,0.f,0.f},{0.f,0.f,0.f,0.f},{0.f,0.f,0.f,0.f},{0.f,0.f,0.f,0.f}};
    const __bf16* W0 = Wb;                // W_l_tl
    const __bf16* W2 = Wb + 2 * D * D;    // W_l_ll
    const __bf16* W3 = Wb + 3 * D * D;    // W_r_tl + W_r_ll
#pragma unroll
    for (int kc = 0; kc < 4; ++kc) {
#pragma unroll
        for (int nt = 0; nt < 4; ++nt) {
            int n = n0 + nt * 16 + m15;
            bf16x8 b0 = *reinterpret_cast<const bf16x8*>(W0 + n * D + kc * 32 + q * 8);
            bf16x8 b2 = *reinterpret_cast<const bf16x8*>(W2 + n * D + kc * 32 + q * 8);
            bf16x8 b3 = *reinterpret_cast<const bf16x8*>(W3 + n * D + kc * 32 + q * 8);
            acc[nt] = __builtin_amdgcn_mfma_f32_16x16x32_bf16(aT[kc], b0, acc[nt], 0, 0, 0);
            acc[nt] = __builtin_amdgcn_mfma_f32_16x16x32_bf16(aL[kc], b2, acc[nt], 0, 0, 0);
            acc[nt] = __builtin_amdgcn_mfma_f32_16x16x32_bf16(aXl[kc], b3, acc[nt], 0, 0, 0);
        }
    }
#pragma unroll
    for (int nt = 0; nt < 4; ++nt) {
        float bias = bias_sum[n0 + nt * 16 + m15];
#pragma unroll
        for (int rg = 0; rg < 4; ++rg) {
            int row = r0 + mtile * 16 + q * 4 + rg;
            if (row < NL)
                outLabel[(size_t)row * D + n0 + nt * 16 + m15] = fmaxf(acc[nt][rg] + bias, 0.0f);
        }
    }
}

// ---------------------------------------------------------------------------
// Supervision-edge dot products: 32 lanes per edge, float4 per lane,
// shuffle-reduce within the 32-lane group.
// ---------------------------------------------------------------------------
__global__ __launch_bounds__(256) void pred_kernel(
    const float* __restrict__ outTitle, const float* __restrict__ outLabel,
    const int* __restrict__ elSrc, const int* __restrict__ elDst,
    float* __restrict__ pred, int E)
{
    int idx = blockIdx.x * 256 + threadIdx.x;
    int e = idx >> 5;
    if (e >= E) return;
    int l = idx & 31;
    int s = elSrc[e];
    int d = elDst[e];
    float4 a = *reinterpret_cast<const float4*>(outTitle + (size_t)s * D + l * 4);
    float4 b = *reinterpret_cast<const float4*>(outLabel + (size_t)d * D + l * 4);
    float v = a.x * b.x + a.y * b.y + a.z * b.z + a.w * b.w;
#pragma unroll
    for (int off = 16; off > 0; off >>= 1) v += __shfl_down(v, off, 32);
    if (l == 0) pred[e] = v;
}

// ---------------------------------------------------------------------------
extern "C" void kernel_launch(void* const* d_in, const int* in_sizes, int n_in,
                              void* d_out, int out_size, void* d_ws, size_t ws_size,
                              hipStream_t stream)
{
    const float* x_title       = (const float*)d_in[0];
    const float* label_embed   = (const float*)d_in[1];
    const float* W_l_tl        = (const float*)d_in[2];
    const float* b_l_tl        = (const float*)d_in[3];
    const float* W_r_tl        = (const float*)d_in[4];
    const float* W_l_ll        = (const float*)d_in[5];
    const float* b_l_ll        = (const float*)d_in[6];
    const float* W_r_ll        = (const float*)d_in[7];
    const int*   label_node_id = (const int*)d_in[8];
    const int*   ta_src        = (const int*)d_in[9];
    const int*   ta_dst        = (const int*)d_in[10];
    const int*   rev_src       = (const int*)d_in[11];
    const int*   rev_dst       = (const int*)d_in[12];
    const int*   ll_src        = (const int*)d_in[13];
    const int*   ll_dst        = (const int*)d_in[14];
    const int*   el_src        = (const int*)d_in[15];
    const int*   el_dst        = (const int*)d_in[16];

    float* out       = (float*)d_out;
    float* pred      = out;                        // [ELBL]
    float* out_title = out + ELBL;                 // [NT*D] — doubles as meanRev
    float* out_label = out_title + (size_t)NT * D; // [NL*D] — doubles as meanTa

    // Workspace layout (16B-aligned pieces).
    __bf16* Wb      = (__bf16*)d_ws;                       // 4*D*D bf16 = 128 KiB
    float*  bias_sum= (float*)(Wb + 4 * D * D);            // 128 floats
    float*  meanLl  = bias_sum + D;                        // NL*D floats
    int*    cntTa   = (int*)(meanLl + (size_t)NL * D);     // NL
    int*    cntLl   = cntTa + NL;                          // NL
    int*    cntRev  = cntLl + NL;                          // NT
    int*    gcnt    = cntRev + NT;                         // 3
    int*    curTa   = gcnt + 3;                            // NL
    int*    curLl   = curTa + NL;                          // NL
    int*    curRev  = curLl + NL;                          // NT
    int*    csrTa   = curRev + NT;                         // ETA
    int*    csrLl   = csrTa + ETA;                         // ELL
    int*    csrRev  = csrLl + ELL;                         // EREV

    // Zero degree counters + the 3 global cursors (contiguous).
    hipMemsetAsync(cntTa, 0, (size_t)(NL + NL + NT + 3) * sizeof(int), stream);

    prep_weights<<<(D * D + 255) / 256, 256, 0, stream>>>(
        W_l_tl, W_r_tl, W_l_ll, W_r_ll, b_l_tl, b_l_ll, Wb, bias_sum);

    // Degree histograms.
    count_kernel<<<(ETA  + 255) / 256, 256, 0, stream>>>(ta_dst,  cntTa,  ETA);
    count_kernel<<<(ELL  + 255) / 256, 256, 0, stream>>>(ll_dst,  cntLl,  ELL);
    count_kernel<<<(EREV + 255) / 256, 256, 0, stream>>>(rev_dst, cntRev, EREV);

    // Segment allocation (order-free, one atomic per wave).
    alloc_kernel<<<(NL + 255) / 256, 256, 0, stream>>>(cntTa,  curTa,  gcnt + 0, NL);
    alloc_kernel<<<(NL + 255) / 256, 256, 0, stream>>>(cntLl,  curLl,  gcnt + 1, NL);
    alloc_kernel<<<(NT + 255) / 256, 256, 0, stream>>>(cntRev, curRev, gcnt + 2, NT);

    // CSR fills (cursor becomes segment end).
    fill_kernel<<<(ETA  + 255) / 256, 256, 0, stream>>>(ta_src,  ta_dst,  nullptr,       curTa,  csrTa,  ETA);
    fill_kernel<<<(ELL  + 255) / 256, 256, 0, stream>>>(ll_src,  ll_dst,  label_node_id, curLl,  csrLl,  ELL);
    fill_kernel<<<(EREV + 255) / 256, 256, 0, stream>>>(rev_src, rev_dst, label_node_id, curRev, csrRev, EREV);

    // Gather-based segmented means (no atomics).
    agg_kernel<<<(NL + 3) / 4, 256, 0, stream>>>(x_title,     csrTa,  cntTa,  curTa,  out_label /*meanTa*/, NL);
    agg_kernel<<<(NL + 3) / 4, 256, 0, stream>>>(label_embed, csrLl,  cntLl,  curLl,  meanLl,               NL);
    agg_kernel<<<(NT + 3) / 4, 256, 0, stream>>>(label_embed, csrRev, cntRev, curRev, out_title /*meanRev*/, NT);

    // MFMA linear layers + bias + ReLU (in-place over mean regions).
    gemm_label_mfma<<<(NL + 31) / 32, 256, 0, stream>>>(
        out_label, meanLl, label_embed, label_node_id, Wb, bias_sum, out_label);
    gemm_title_mfma<<<NT / 32, 256, 0, stream>>>(
        out_title, x_title, Wb, b_l_tl, out_title);

    // Supervision-edge dot products.
    pred_kernel<<<(ELBL * 32) / 256, 256, 0, stream>>>(
        out_title, out_label, el_src, el_dst, pred, ELBL);
}